// Round 8
// baseline (740.839 us; speedup 1.0000x reference)
//
#include <hip/hip_runtime.h>
#include <math.h>

// Problem dims (fixed by setup_inputs)
#define DD    512
#define CNUM  64
#define SHOTS 16
#define NSUP  1024
#define QNQ   2048
#define REGP  0.1f
#define XKS   4        // xmu split-K parts
#define NBLK  256      // f_setup persistent grid (co-residency: 34.8KB LDS -> 4 blk/CU, cap 1024)

// ---------------- workspace layout (in floats) ----------------
static constexpr size_t OFF_L     = 0;                       // 512*512
static constexpr size_t OFF_W     = OFF_L     + 512*512;     // 512*512
static constexpr size_t OFF_MU    = OFF_W     + 512*512;     // 64*512
static constexpr size_t OFF_Y     = OFF_MU    + 64*512;      // 3136*512
static constexpr size_t OFF_Z     = OFF_Y     + 3136*512;    // 3136
static constexpr size_t OFF_WM    = OFF_Z     + 3136;        // 512
static constexpr size_t OFF_U     = OFF_WM    + 512;         // 512
static constexpr size_t OFF_CONST = OFF_U     + 512;         // 16 floats
static constexpr size_t OFF_BAR   = OFF_CONST + 16;          // 2 uints (memset to 0)
static constexpr size_t OFF_IDX   = OFF_BAR   + 16;          // 1024 ints
static constexpr size_t OFF_RMAP  = OFF_IDX   + 1024;        // 1088 ints
static constexpr size_t OFF_VMU   = OFF_RMAP  + 1088;        // 1088
static constexpr size_t OFF_MUBMU = OFF_VMU   + 1088;        // 64
static constexpr size_t OFF_MUN   = OFF_MUBMU + 64;          // 64
static constexpr size_t OFF_MINV  = OFF_MUN   + 64;          // 64*289
static constexpr size_t OFF_BIAS  = OFF_MINV  + 64*289;      // 64
static constexpr size_t OFF_QB    = OFF_BIAS  + 64;          // 2048
static constexpr size_t OFF_QNRM  = OFF_QB    + 2048;        // 2048
static constexpr size_t OFF_XMU   = OFF_QNRM  + 2048;        // XKS*2048*64
static constexpr size_t OFF_RG    = OFF_XMU   + (size_t)XKS*2048*64; // 1088*2048
static constexpr size_t OFF_RG2   = OFF_RG    + 1088*2048;   // 1088*2048

// consts: 0 kap, 1 scale, 2 common, 3 coef, 4 bias0, 5 jlast,
// 6 cmu_m, 7 cmu_x, 8 D*log(scale), 9 Jinv_last, 10 c_sm, 11 logdetB

// ---------------- software grid barrier (generation counter) ----------------
__device__ __forceinline__ void gbar(unsigned* bar) {
  __syncthreads();
  __threadfence();
  if (threadIdx.x == 0) {
    unsigned g = __hip_atomic_load(&bar[1], __ATOMIC_ACQUIRE, __HIP_MEMORY_SCOPE_AGENT);
    unsigned a = __hip_atomic_fetch_add(&bar[0], 1u, __ATOMIC_ACQ_REL, __HIP_MEMORY_SCOPE_AGENT);
    if (a + 1 == (unsigned)NBLK) {
      __hip_atomic_store(&bar[0], 0u, __ATOMIC_RELAXED, __HIP_MEMORY_SCOPE_AGENT);
      __hip_atomic_fetch_add(&bar[1], 1u, __ATOMIC_ACQ_REL, __HIP_MEMORY_SCOPE_AGENT);
    } else {
      while (__hip_atomic_load(&bar[1], __ATOMIC_ACQUIRE, __HIP_MEMORY_SCOPE_AGENT) == g) {
        __builtin_amdgcn_s_sleep(1);
      }
    }
  }
  __threadfence();
  __syncthreads();
}

// 64x64 NN GEMM tile on caller-provided LDS (stride 68): Cd = sgn * A[:, k0:k1] * B[k0:k1, :]
__device__ __forceinline__ void nn64_sh(float* As, float* Bs,
    const float* __restrict__ A, int lda, const float* __restrict__ B, int ldb,
    float* __restrict__ Cd, int ldc, int k0, int k1, float sgn) {
  int tid = threadIdx.x, tr = tid >> 4, tc = tid & 15;
  float acc[4][4] = {};
  for (int kc = k0; kc < k1; kc += 64) {
    #pragma unroll
    for (int p = 0; p < 4; p++) {
      int f4 = tid + 256 * p;
      int row = f4 >> 4, c4 = f4 & 15;
      *(float4*)&As[row * 68 + c4 * 4] = *(const float4*)(A + (size_t)row * lda + kc + c4 * 4);
      *(float4*)&Bs[row * 68 + c4 * 4] = *(const float4*)(B + (size_t)(kc + row) * ldb + c4 * 4);
    }
    __syncthreads();
    #pragma unroll
    for (int kk = 0; kk < 64; kk++) {
      float a[4];
      #pragma unroll
      for (int x = 0; x < 4; x++) a[x] = As[(tr * 4 + x) * 68 + kk];
      float4 bv = *(const float4*)&Bs[kk * 68 + tc * 4];
      float b[4] = {bv.x, bv.y, bv.z, bv.w};
      #pragma unroll
      for (int x = 0; x < 4; x++)
        #pragma unroll
        for (int y = 0; y < 4; y++) acc[x][y] += a[x] * b[y];
    }
    __syncthreads();
  }
  #pragma unroll
  for (int x = 0; x < 4; x++) {
    float4 v = make_float4(sgn * acc[x][0], sgn * acc[x][1],
                           sgn * acc[x][2], sgn * acc[x][3]);
    *(float4*)(Cd + (size_t)(tr * 4 + x) * ldc + tc * 4) = v;
  }
}

// ============ F_SETUP: init -> mu/diag -> trinv doubling -> wm -> u (one launch) ============
__global__ __launch_bounds__(256) void f_setup(
    const float* tdiag, const float* tlow, const float* kappa, const float* nu,
    const int* labels, const float* Xs, const float* m,
    float* L, float* W, float* cst, int* idx, int* rowmap,
    float* mu, float* mun, float* T, float* wm, float* u, unsigned* bar) {
  __shared__ float sh[2 * 64 * 68];   // 34.8 KB, aliased per phase
  int b = blockIdx.x, tid = threadIdx.x;

  // ---- P0: L/W init + consts + classidx/rowmap ----
  for (int item = b; item < 1024; item += NBLK) {
    int t = item * 256 + tid;
    int i = t >> 9, j = t & 511;
    L[t] = (i == j) ? fabsf(tdiag[i]) : (i > j ? tlow[t] : 0.0f);
    W[t] = 0.0f;
  }
  if (b == 64 && tid == 0) {
    float kap = fabsf(kappa[0]) + 1e-6f;
    float nu_ = fmaxf(nu[0], (float)(DD - 1) + 1e-6f);
    float common = nu_ + (float)SHOTS + 1.0f - (float)DD;
    float scale = (kap + SHOTS + 1.0f) / ((nu_ + SHOTS - DD + 1.0f) * (kap + SHOTS));
    cst[0] = kap;
    cst[1] = scale;
    cst[2] = common;
    cst[3] = 0.5f * (common + DD);
    cst[4] = lgammaf(0.5f * (common + DD)) - lgammaf(0.5f * common)
             - 0.5f * (float)DD * logf(common);
    cst[5] = -(kap + SHOTS);
    cst[6] = kap / (kap + SHOTS);
    cst[7] = 1.0f / (kap + SHOTS);
    cst[8] = (float)DD * logf(scale);
    cst[9] = -1.0f / (kap + SHOTS);
  }
  if (b < 64) {
    int c = b;
    if (tid < 64) {
      int lane = tid, cnt = 0;
      for (int i0 = 0; i0 < NSUP; i0 += 64) {
        int lab = labels[i0 + lane];
        unsigned long long mm = __ballot(lab == c);
        if (lab == c) {
          int pos = cnt + __popcll(mm & ((1ull << lane) - 1ull));
          if (pos < SHOTS) idx[c * SHOTS + pos] = i0 + lane;
        }
        cnt += __popcll(mm);
      }
    }
    __syncthreads();
    if (tid < 17)
      rowmap[c * 17 + tid] = (tid < SHOTS) ? (QNQ + idx[c * SHOTS + tid])
                                           : (QNQ + NSUP + c);
  }
  gbar(bar);

  // ---- P1: mu/mun (blocks 0..63) + diag 64-inverses (blocks 64..71) ----
  if (b < 64) {
    float* red = sh;
    int c = b;
    float cm = cst[6], cx = cst[7];
    float acc = 0.0f;
    for (int d = tid; d < DD; d += 256) {
      float s = 0.0f;
      for (int sh_ = 0; sh_ < SHOTS; sh_++)
        s += Xs[(size_t)idx[c * SHOTS + sh_] * DD + d];
      float v = cm * m[d] + cx * s;
      mu[(size_t)c * DD + d] = v;
      acc += v * v;
    }
    red[tid] = acc;
    __syncthreads();
    for (int off = 128; off > 0; off >>= 1) {
      if (tid < off) red[tid] += red[tid + off];
      __syncthreads();
    }
    if (tid == 0) mun[c] = red[0];
  } else if (b < 72) {
    int jb = b - 64;
    float* Ld = sh;             // [64][68]
    float* Wd = sh + 64 * 68;   // [64][68]
    const float* Lblk = L + (size_t)(jb * 64) * DD + jb * 64;
    for (int t = tid; t < 4096; t += 256)
      Ld[(t >> 6) * 68 + (t & 63)] = Lblk[(size_t)(t >> 6) * DD + (t & 63)];
    __syncthreads();
    if (tid < 64) {
      // thread t owns column t of the inverse
      for (int i = 0; i < 64; i++) {
        float w = (i == tid) ? 1.0f : 0.0f;
        for (int k = 0; k < i; k++) w -= Ld[i * 68 + k] * Wd[k * 68 + tid];
        Wd[i * 68 + tid] = w / Ld[i * 68 + i];
      }
    }
    __syncthreads();
    float* Wblk = W + (size_t)(jb * 64) * DD + jb * 64;
    for (int t = tid; t < 4096; t += 256)
      Wblk[(size_t)(t >> 6) * DD + (t & 63)] = Wd[(t >> 6) * 68 + (t & 63)];
  }
  gbar(bar);

  // ---- P2..P7: recursive doubling levels 128/256/512, T then X per level ----
  for (int s = 128; s <= 512; s <<= 1) {
    int h = s >> 1, tiles = h >> 6, per = tiles * tiles, supers = 512 / s;
    int n = supers * per;
    if (b < n) {
      int g = b / per, rem = b % per, ti = rem / tiles, tj = rem % tiles;
      int base = g * s;
      const float* A = L + (size_t)(base + h + ti * 64) * DD + base;
      const float* B = W + (size_t)base * DD + base + tj * 64;
      float* Cd = T + (size_t)g * h * h + (size_t)(ti * 64) * h + tj * 64;
      nn64_sh(sh, sh + 64 * 68, A, DD, B, DD, Cd, h, tj * 64, h, 1.0f);
    }
    gbar(bar);
    if (b < n) {
      int g = b / per, rem = b % per, ti = rem / tiles, tj = rem % tiles;
      int base = g * s;
      const float* A = W + (size_t)(base + h + ti * 64) * DD + base + h;
      const float* B = T + (size_t)g * h * h + tj * 64;
      float* Cd = W + (size_t)(base + h + ti * 64) * DD + base + tj * 64;
      nn64_sh(sh, sh + 64 * 68, A, DD, B, h, Cd, DD, 0, (ti + 1) * 64, -1.0f);
    }
    gbar(bar);
  }

  // ---- P8: wm[row] = W[row,:] . m  (4 rows/block, blocks 0..127) ----
  if (b < 128) {
    int wave = tid >> 6, lane = tid & 63;
    int row = b * 4 + wave;
    float s = 0.0f;
    for (int j = lane; j < DD; j += 64) s += W[(size_t)row * DD + j] * m[j];
    for (int off = 32; off > 0; off >>= 1) s += __shfl_down(s, off);
    if (lane == 0) wm[row] = s;
  }
  gbar(bar);

  // ---- P9: u[j] = W[:,j] . wm  + Sherman-Morrison consts ----
  {
    float* red = sh;
    float* red2 = sh + 256;
    for (int item = b; item < 513; item += NBLK) {
      if (item < 512) {
        float s = 0.0f;
        for (int i = tid; i < DD; i += 256) s += W[(size_t)i * DD + item] * wm[i];
        red[tid] = s;
        __syncthreads();
        for (int off = 128; off > 0; off >>= 1) {
          if (tid < off) red[tid] += red[tid + off];
          __syncthreads();
        }
        if (tid == 0) u[item] = red[0];
        __syncthreads();
      } else {
        float a = 0.0f, l = 0.0f;
        for (int t = tid; t < DD; t += 256) {
          float w = wm[t]; a += w * w;
          l += logf(fabsf(L[(size_t)t * DD + t]));
        }
        red[tid] = a; red2[tid] = l;
        __syncthreads();
        for (int off = 128; off > 0; off >>= 1) {
          if (tid < off) { red[tid] += red[tid + off]; red2[tid] += red2[tid + off]; }
          __syncthreads();
        }
        if (tid == 0) {
          float kap = cst[0], ss = red[0];
          cst[10] = kap / (1.0f + kap * ss);
          cst[11] = 2.0f * red2[0] + logf(1.0f + kap * ss);
        }
        __syncthreads();
      }
    }
  }
}

#define GBK 16
// ============ F3: Y-GEMM (64x64, tri-skip) + xmu (one launch) ============
__global__ __launch_bounds__(256) void f_y_xmu(const float* __restrict__ Xq,
    const float* __restrict__ Xs, const float* __restrict__ Mu,
    const float* __restrict__ W,
    float* __restrict__ Y, float* __restrict__ xmup) {
  __shared__ float As[GBK][68];
  __shared__ float Bs[GBK][68];
  int b = blockIdx.x, tid = threadIdx.x;
  if (b < 392) {            // Y = [Xq; Xs; mu] @ W^T; 49 m-tiles x 8 n-tiles, 64x64
    int mt = b >> 3, nt = b & 7;
    int bm = mt * 64, bn = nt * 64;
    const float* A; int aOff;
    if (bm < QNQ)             { A = Xq; aOff = bm; }
    else if (bm < QNQ + NSUP) { A = Xs; aOff = bm - QNQ; }
    else                      { A = Mu; aOff = bm - QNQ - NSUP; }
    int tr = tid >> 4, tc = tid & 15;
    float acc[4][4] = {};
    int kend = bn + 64;     // W lower-triangular
    for (int k0 = 0; k0 < kend; k0 += GBK) {
      int row = tid >> 2, k4 = tid & 3;
      float4 v = *(const float4*)(A + (size_t)(aOff + row) * DD + k0 + k4 * 4);
      As[k4 * 4 + 0][row] = v.x; As[k4 * 4 + 1][row] = v.y;
      As[k4 * 4 + 2][row] = v.z; As[k4 * 4 + 3][row] = v.w;
      float4 w = *(const float4*)(W + (size_t)(bn + row) * DD + k0 + k4 * 4);
      Bs[k4 * 4 + 0][row] = w.x; Bs[k4 * 4 + 1][row] = w.y;
      Bs[k4 * 4 + 2][row] = w.z; Bs[k4 * 4 + 3][row] = w.w;
      __syncthreads();
      #pragma unroll
      for (int kk = 0; kk < GBK; kk++) {
        float4 a0 = *(const float4*)&As[kk][tr * 4];
        float4 b0 = *(const float4*)&Bs[kk][tc * 4];
        float a[4] = {a0.x, a0.y, a0.z, a0.w};
        float bb[4] = {b0.x, b0.y, b0.z, b0.w};
        #pragma unroll
        for (int x = 0; x < 4; x++)
          #pragma unroll
          for (int y = 0; y < 4; y++) acc[x][y] += a[x] * bb[y];
      }
      __syncthreads();
    }
    #pragma unroll
    for (int x = 0; x < 4; x++) {
      float4 v = make_float4(acc[x][0], acc[x][1], acc[x][2], acc[x][3]);
      *(float4*)(Y + (size_t)(bm + tr * 4 + x) * DD + bn + tc * 4) = v;
    }
  } else {                  // xmu partials: 32 q-rows, split-K=4
    int xb = b - 392;
    int bm = (xb & 63) * 32, kq = xb >> 6;
    int tr = tid >> 4, tc = tid & 15;
    float acc[2][4] = {};
    int k0s = kq * (DD / XKS), k0e = k0s + DD / XKS;
    for (int k0 = k0s; k0 < k0e; k0 += GBK) {
      if (tid < 128) {
        int row = tid >> 2, k4 = tid & 3;
        float4 v = *(const float4*)(Xq + (size_t)(bm + row) * DD + k0 + k4 * 4);
        As[k4 * 4 + 0][row] = v.x; As[k4 * 4 + 1][row] = v.y;
        As[k4 * 4 + 2][row] = v.z; As[k4 * 4 + 3][row] = v.w;
      }
      {
        int row = tid >> 2, k4 = tid & 3;
        float4 v = *(const float4*)(Mu + (size_t)row * DD + k0 + k4 * 4);
        Bs[k4 * 4 + 0][row] = v.x; Bs[k4 * 4 + 1][row] = v.y;
        Bs[k4 * 4 + 2][row] = v.z; Bs[k4 * 4 + 3][row] = v.w;
      }
      __syncthreads();
      #pragma unroll
      for (int kk = 0; kk < GBK; kk++) {
        float a[2] = {As[kk][tr * 2], As[kk][tr * 2 + 1]};
        float4 b0 = *(const float4*)&Bs[kk][tc * 4];
        float bb[4] = {b0.x, b0.y, b0.z, b0.w};
        #pragma unroll
        for (int x = 0; x < 2; x++)
          #pragma unroll
          for (int y = 0; y < 4; y++) acc[x][y] += a[x] * bb[y];
      }
      __syncthreads();
    }
    #pragma unroll
    for (int x = 0; x < 2; x++) {
      int q = bm + tr * 2 + x;
      float4 v = make_float4(acc[x][0], acc[x][1], acc[x][2], acc[x][3]);
      *(float4*)(xmup + ((size_t)kq * QNQ + q) * CNUM + tc * 4) = v;
    }
  }
}

// ============ F5: Rg GEMM (64x64, 4x4/thread, split-K=2 -> 1088 blocks) + z ============
__global__ __launch_bounds__(256) void f_z_rg(const float* __restrict__ Y,
    const int* __restrict__ rowmap, const float* __restrict__ Xq,
    const float* __restrict__ Xs, const float* __restrict__ mu,
    const float* __restrict__ u, const float* __restrict__ cst,
    float* __restrict__ Rg, float* __restrict__ Rg2,
    float* __restrict__ z, float* __restrict__ qn, float* __restrict__ qB) {
  __shared__ float As[GBK][68];
  __shared__ float Bs[GBK][68];
  int b = blockIdx.x, tid = threadIdx.x;
  if (b < 1088) {           // 17 m-tiles x 32 n-tiles x 2 K-halves, 64x64 out
    int half = b / 544, rem = b % 544;
    int bm = (rem >> 5) * 64, bn = (rem & 31) * 64;
    float* out = half ? Rg2 : Rg;
    int tr = tid >> 4, tc = tid & 15;
    int srow = rowmap[bm + (tid >> 2)];       // gathered A row for staging
    float acc[4][4] = {};
    int k0s = half * 256;
    for (int k0 = k0s; k0 < k0s + 256; k0 += GBK) {
      int row = tid >> 2, k4 = tid & 3;
      float4 v = *(const float4*)(Y + (size_t)srow * DD + k0 + k4 * 4);
      As[k4 * 4 + 0][row] = v.x; As[k4 * 4 + 1][row] = v.y;
      As[k4 * 4 + 2][row] = v.z; As[k4 * 4 + 3][row] = v.w;
      float4 w = *(const float4*)(Y + (size_t)(bn + row) * DD + k0 + k4 * 4);
      Bs[k4 * 4 + 0][row] = w.x; Bs[k4 * 4 + 1][row] = w.y;
      Bs[k4 * 4 + 2][row] = w.z; Bs[k4 * 4 + 3][row] = w.w;
      __syncthreads();
      #pragma unroll
      for (int kk = 0; kk < GBK; kk++) {
        float4 a0 = *(const float4*)&As[kk][tr * 4];
        float4 b0 = *(const float4*)&Bs[kk][tc * 4];
        float a[4] = {a0.x, a0.y, a0.z, a0.w};
        float bb[4] = {b0.x, b0.y, b0.z, b0.w};
        #pragma unroll
        for (int x = 0; x < 4; x++)
          #pragma unroll
          for (int y = 0; y < 4; y++) acc[x][y] += a[x] * bb[y];
      }
      __syncthreads();
    }
    #pragma unroll
    for (int x = 0; x < 4; x++) {
      float4 v = make_float4(acc[x][0], acc[x][1], acc[x][2], acc[x][3]);
      *(float4*)(out + (size_t)(bm + tr * 4 + x) * QNQ + bn + tc * 4) = v;
    }
  } else {
    int wave = tid / 64, lane = tid % 64;
    int row = (b - 1088) * 4 + wave;
    if (row >= 3136) return;
    bool isq = row < QNQ;
    const float* src = isq ? Xq + (size_t)row * DD
                     : (row < QNQ + NSUP) ? Xs + (size_t)(row - QNQ) * DD
                     : mu + (size_t)(row - QNQ - NSUP) * DD;
    const float* yr = Y + (size_t)row * DD;
    float s = 0.0f, s1 = 0.0f, s2 = 0.0f;
    for (int j4 = lane; j4 < 128; j4 += 64) {
      float4 v = *(const float4*)(src + j4 * 4);
      float4 uu = *(const float4*)(u + j4 * 4);
      s += v.x * uu.x + v.y * uu.y + v.z * uu.z + v.w * uu.w;
      if (isq) {
        s1 += v.x * v.x + v.y * v.y + v.z * v.z + v.w * v.w;
        float4 yv = *(const float4*)(yr + j4 * 4);
        s2 += yv.x * yv.x + yv.y * yv.y + yv.z * yv.z + yv.w * yv.w;
      }
    }
    for (int off = 32; off > 0; off >>= 1) {
      s += __shfl_down(s, off);
      s1 += __shfl_down(s1, off);
      s2 += __shfl_down(s2, off);
    }
    if (lane == 0) {
      z[row] = s;
      if (isq) {
        qn[row] = s1;
        qB[row] = s2 - cst[10] * s * s;
      }
    }
  }
}

// ============ F6: per-class Gram + inline 17x17 GJ inverse + bias ============
#define YSTRIDE 516
__global__ __launch_bounds__(256) void k_gramminv(const float* Y, const float* z,
    const int* rowmap, const float* cst, float* Vmu, float* muBmu,
    float* Minv, float* bias) {
  __shared__ float Ys[17 * YSTRIDE];
  __shared__ float zs[17];
  __shared__ float aug[17][35];
  __shared__ float colk[17];
  __shared__ int pivrow;
  __shared__ float detacc;
  int c = blockIdx.x, tid = threadIdx.x;
  for (int t = tid; t < 17 * 128; t += 256) {
    int r = t >> 7, col = t & 127;
    *(float4*)&Ys[r * YSTRIDE + col * 4] =
        *(const float4*)(Y + (size_t)rowmap[c * 17 + r] * DD + col * 4);
  }
  if (tid < 17) zs[tid] = z[rowmap[c * 17 + tid]];
  __syncthreads();
  float csm = cst[10];
  for (int e = tid; e < 289; e += 256) {
    int a = e / 17, bb = e % 17;
    const float* ra = &Ys[a * YSTRIDE];
    const float* rb = &Ys[bb * YSTRIDE];
    float s = 0.0f;
    for (int k = 0; k < 128; k++) {
      float4 va = *(const float4*)&ra[k * 4];
      float4 vb = *(const float4*)&rb[k * 4];
      s += va.x * vb.x + va.y * vb.y + va.z * vb.z + va.w * vb.w;
    }
    float g = s - csm * zs[a] * zs[bb];
    if (a == bb) g += (a < 16) ? 1.0f : cst[9];
    aug[a][bb] = g;
    aug[a][17 + bb] = (a == bb) ? 1.0f : 0.0f;
  }
  __syncthreads();
  if (tid < 17) {
    float gv = aug[tid][16];
    if (tid == 16) gv -= cst[9];
    Vmu[c * 17 + tid] = gv;
    if (tid == 16) muBmu[c] = gv;
  }
  if (tid == 0) detacc = 0.0f;
  __syncthreads();
  for (int k = 0; k < 17; k++) {
    if (tid == 0) {
      int p = k; float best = fabsf(aug[k][k]);
      for (int r = k + 1; r < 17; r++) {
        float v = fabsf(aug[r][k]);
        if (v > best) { best = v; p = r; }
      }
      pivrow = p;
    }
    __syncthreads();
    int p = pivrow;
    if (p != k) {
      for (int cc = tid; cc < 34; cc += 256) {
        float tmp = aug[k][cc]; aug[k][cc] = aug[p][cc]; aug[p][cc] = tmp;
      }
    }
    __syncthreads();
    if (tid == 0) detacc += logf(fabsf(aug[k][k]));
    if (tid < 17) colk[tid] = aug[tid][k];
    __syncthreads();
    float invp = 1.0f / aug[k][k];
    for (int cc = tid; cc < 34; cc += 256) aug[k][cc] *= invp;
    __syncthreads();
    for (int t = tid; t < 17 * 34; t += 256) {
      int r = t / 34, cc = t % 34;
      if (r != k) aug[r][cc] -= colk[r] * aug[k][cc];
    }
    __syncthreads();
  }
  for (int t = tid; t < 289; t += 256) Minv[(size_t)c * 289 + t] = aug[t / 17][17 + t % 17];
  if (tid == 0) {
    float slog = logf(fabsf(cst[5])) + detacc;
    float logdetSigma = cst[8] + cst[11] + slog;
    bias[c] = cst[4] - 0.5f * logdetSigma;
  }
}

// final epilogue: Woodbury-corrected Mahalanobis -> logits[q,c]
__global__ __launch_bounds__(256) void k_logits(const float* __restrict__ Rg,
    const float* __restrict__ Rg2, const float* z, const int* rowmap,
    const float* Vmu, const float* muBmu, const float* mun, const float* qB,
    const float* qn, const float* xmup, const float* Minv, const float* bias,
    const float* cst, float* out) {
  __shared__ float Ms[289], Vs[17], Zs[17];
  int c = blockIdx.y;
  int q = blockIdx.x * 256 + threadIdx.x;
  for (int t = threadIdx.x; t < 289; t += 256) Ms[t] = Minv[(size_t)c * 289 + t];
  if (threadIdx.x < 17) {
    Vs[threadIdx.x] = Vmu[c * 17 + threadIdx.x];
    Zs[threadIdx.x] = z[rowmap[c * 17 + threadIdx.x]];
  }
  __syncthreads();
  float csm = cst[10], scale = cst[1], common = cst[2], coef = cst[3];
  float zq = z[q];
  float r[17];
  float xBmu = 0.0f;
  for (int a = 0; a < 17; a++) {
    size_t off = (size_t)(c * 17 + a) * QNQ + q;
    float raw = Rg[off] + Rg2[off] - csm * Zs[a] * zq;
    if (a == 16) xBmu = raw;
    r[a] = raw - Vs[a];
  }
  float quadB = qB[q] - 2.0f * xBmu + muBmu[c];
  float corr = 0.0f;
  for (int a = 0; a < 17; a++) {
    float e = 0.0f;
    for (int b = 0; b < 17; b++) e += Ms[a * 17 + b] * r[b];
    corr += r[a] * e;
  }
  float distB = (quadB - corr) / scale;
  float xm = 0.0f;
  #pragma unroll
  for (int p = 0; p < XKS; p++)
    xm += xmup[((size_t)p * QNQ + q) * CNUM + c];
  float dn = qn[q] - 2.0f * xm + mun[c];
  float dist = (1.0f - REGP) * distB + REGP * dn;
  out[(size_t)q * CNUM + c] = bias[c] - coef * log1pf(dist / common);
}

// ---------------- host ----------------
extern "C" void kernel_launch(void* const* d_in, const int* in_sizes, int n_in,
                              void* d_out, int out_size, void* d_ws, size_t ws_size,
                              hipStream_t stream) {
  const float* Xs    = (const float*)d_in[0];
  const int*   labels= (const int*)d_in[1];
  const float* Xq    = (const float*)d_in[2];
  const float* m     = (const float*)d_in[3];
  const float* kappa = (const float*)d_in[4];
  const float* nu    = (const float*)d_in[5];
  const float* tdiag = (const float*)d_in[6];
  const float* tlow  = (const float*)d_in[7];
  float* ws = (float*)d_ws;
  float* L    = ws + OFF_L;
  float* W    = ws + OFF_W;
  float* mu   = ws + OFF_MU;
  float* Y    = ws + OFF_Y;
  float* z    = ws + OFF_Z;
  float* wm   = ws + OFF_WM;
  float* u    = ws + OFF_U;
  float* cst  = ws + OFF_CONST;
  unsigned* bar = (unsigned*)(ws + OFF_BAR);
  int*   idx  = (int*)(ws + OFF_IDX);
  int*   rmap = (int*)(ws + OFF_RMAP);
  float* Vmu  = ws + OFF_VMU;
  float* muBmu= ws + OFF_MUBMU;
  float* mun  = ws + OFF_MUN;
  float* Minv = ws + OFF_MINV;
  float* bias = ws + OFF_BIAS;
  float* qB   = ws + OFF_QB;
  float* qn   = ws + OFF_QNRM;
  float* xmup = ws + OFF_XMU;
  float* Rg   = ws + OFF_RG;
  float* Rg2  = ws + OFF_RG2;
  float* Ttmp = ws + OFF_RG;       // trinv scratch, reused (Rg written later)
  float* out  = (float*)d_out;

  // zero the software grid-barrier state (graph-capture-safe)
  hipMemsetAsync(bar, 0, 8, stream);
  // one persistent launch: init -> mu/diag -> trinv doubling -> wm -> u/SM-consts
  f_setup<<<NBLK, 256, 0, stream>>>(tdiag, tlow, kappa, nu, labels, Xs, m,
                                    L, W, cst, idx, rmap, mu, mun, Ttmp, wm, u, bar);
  // Y GEMM (64x64, tri-skip) + xmu partials
  f_y_xmu<<<648, 256, 0, stream>>>(Xq, Xs, mu, W, Y, xmup);
  // Rg split-K GEMM (1088 blocks) + z/qn/qB
  f_z_rg<<<1088 + 784, 256, 0, stream>>>(Y, rmap, Xq, Xs, mu, u, cst,
                                         Rg, Rg2, z, qn, qB);
  // Gram + 17x17 inverse + bias
  k_gramminv<<<64, 256, 0, stream>>>(Y, z, rmap, cst, Vmu, muBmu, Minv, bias);
  k_logits<<<dim3(QNQ / 256, CNUM), 256, 0, stream>>>(Rg, Rg2, z, rmap, Vmu, muBmu,
                                                      mun, qB, qn, xmup, Minv, bias,
                                                      cst, out);
  (void)in_sizes; (void)n_in; (void)out_size; (void)ws_size;
}

// Round 9
// 305.017 us; speedup vs baseline: 2.4288x; 2.4288x over previous
//
#include <hip/hip_runtime.h>
#include <math.h>

// Problem dims (fixed by setup_inputs)
#define DD    512
#define CNUM  64
#define SHOTS 16
#define NSUP  1024
#define QNQ   2048
#define REGP  0.1f
#define XKS   4      // xmu split-K parts

// ---------------- workspace layout (in floats) ----------------
static constexpr size_t OFF_L     = 0;                       // 512*512
static constexpr size_t OFF_W     = OFF_L     + 512*512;     // 512*512
static constexpr size_t OFF_MU    = OFF_W     + 512*512;     // 64*512
static constexpr size_t OFF_Y     = OFF_MU    + 64*512;      // 3136*512
static constexpr size_t OFF_Z     = OFF_Y     + 3136*512;    // 3136
static constexpr size_t OFF_WM    = OFF_Z     + 3136;        // 512
static constexpr size_t OFF_U     = OFF_WM    + 512;         // 512
static constexpr size_t OFF_CONST = OFF_U     + 512;         // 16
static constexpr size_t OFF_IDX   = OFF_CONST + 16;          // 1024 ints
static constexpr size_t OFF_RMAP  = OFF_IDX   + 1024;        // 1088 ints
static constexpr size_t OFF_ZG    = OFF_RMAP  + 1088;        // 1088
static constexpr size_t OFF_VMU   = OFF_ZG    + 1088;        // 1088
static constexpr size_t OFF_MUBMU = OFF_VMU   + 1088;        // 64
static constexpr size_t OFF_MUN   = OFF_MUBMU + 64;          // 64
static constexpr size_t OFF_MINV  = OFF_MUN   + 64;          // 64*289
static constexpr size_t OFF_BIAS  = OFF_MINV  + 64*289;      // 64
static constexpr size_t OFF_QB    = OFF_BIAS  + 64;          // 2048
static constexpr size_t OFF_QNRM  = OFF_QB    + 2048;        // 2048
static constexpr size_t OFF_XMU   = OFF_QNRM  + 2048;        // XKS*2048*64
static constexpr size_t OFF_RG    = OFF_XMU   + (size_t)XKS*2048*64; // 1088*2048
static constexpr size_t OFF_RG2   = OFF_RG    + 1088*2048;   // 1088*2048

// consts: 0 kap, 1 scale, 2 common, 3 coef, 4 bias0, 5 jlast,
// 6 cmu_m, 7 cmu_x, 8 D*log(scale), 9 Jinv_last, 10 c_sm, 11 logdetB

// ============ F1: L/W init + consts + classidx + mu/mun + diag-inv ============
// All block ranges are self-sufficient (no cross-block deps within the launch):
// mu blocks re-derive idx locally; diag blocks build their L-tile from inputs.
__global__ __launch_bounds__(256) void f_init(const float* tdiag, const float* tlow,
    const float* kappa, const float* nu, const int* labels, const float* Xs,
    const float* m, float* L, float* W, float* cst, int* idx, int* rowmap,
    float* mu, float* mun) {
  __shared__ float sh[2 * 64 * 68];   // 34.8 KB union
  __shared__ int sidx[SHOTS];
  int b = blockIdx.x, tid = threadIdx.x;
  if (b < 1024) {
    int t = b * 256 + tid;
    int i = t >> 9, j = t & 511;
    L[t] = (i == j) ? fabsf(tdiag[i]) : (i > j ? tlow[t] : 0.0f);
    if ((i >> 6) < (j >> 6)) W[t] = 0.0f;   // only strict-upper 64-blocks need zeros
  } else if (b == 1024) {
    if (tid == 0) {
      float kap = fabsf(kappa[0]) + 1e-6f;
      float nu_ = fmaxf(nu[0], (float)(DD - 1) + 1e-6f);
      float common = nu_ + (float)SHOTS + 1.0f - (float)DD;
      float scale = (kap + SHOTS + 1.0f) / ((nu_ + SHOTS - DD + 1.0f) * (kap + SHOTS));
      cst[0] = kap;
      cst[1] = scale;
      cst[2] = common;
      cst[3] = 0.5f * (common + DD);
      cst[4] = lgammaf(0.5f * (common + DD)) - lgammaf(0.5f * common)
               - 0.5f * (float)DD * logf(common);
      cst[5] = -(kap + SHOTS);
      cst[6] = kap / (kap + SHOTS);
      cst[7] = 1.0f / (kap + SHOTS);
      cst[8] = (float)DD * logf(scale);
      cst[9] = -1.0f / (kap + SHOTS);
    }
  } else if (b < 1089) {
    // classidx + rowmap (global)
    int c = b - 1025;
    if (tid < 64) {
      int lane = tid, cnt = 0;
      for (int i0 = 0; i0 < NSUP; i0 += 64) {
        int lab = labels[i0 + lane];
        unsigned long long mm = __ballot(lab == c);
        if (lab == c) {
          int pos = cnt + __popcll(mm & ((1ull << lane) - 1ull));
          if (pos < SHOTS) idx[c * SHOTS + pos] = i0 + lane;
        }
        cnt += __popcll(mm);
      }
    }
    __syncthreads();
    if (tid < 17)
      rowmap[c * 17 + tid] = (tid < SHOTS) ? (QNQ + idx[c * SHOTS + tid])
                                           : (QNQ + NSUP + c);
  } else if (b < 1153) {
    // mu/mun with locally re-derived idx + kappa coefficients
    int c = b - 1089;
    if (tid < 64) {
      int lane = tid, cnt = 0;
      for (int i0 = 0; i0 < NSUP; i0 += 64) {
        int lab = labels[i0 + lane];
        unsigned long long mm = __ballot(lab == c);
        if (lab == c) {
          int pos = cnt + __popcll(mm & ((1ull << lane) - 1ull));
          if (pos < SHOTS) sidx[pos] = i0 + lane;
        }
        cnt += __popcll(mm);
      }
    }
    __syncthreads();
    float kap = fabsf(kappa[0]) + 1e-6f;
    float cm = kap / (kap + SHOTS), cx = 1.0f / (kap + SHOTS);
    float* red = sh;
    float acc = 0.0f;
    for (int d = tid; d < DD; d += 256) {
      float s = 0.0f;
      for (int sh_ = 0; sh_ < SHOTS; sh_++)
        s += Xs[(size_t)sidx[sh_] * DD + d];
      float v = cm * m[d] + cx * s;
      mu[(size_t)c * DD + d] = v;
      acc += v * v;
    }
    red[tid] = acc;
    __syncthreads();
    for (int off = 128; off > 0; off >>= 1) {
      if (tid < off) red[tid] += red[tid + off];
      __syncthreads();
    }
    if (tid == 0) mun[c] = red[0];
  } else {
    // diag 64x64 inverse, L-tile built directly from tdiag/tlow
    int jb = b - 1153;
    float* Ld = sh;             // [64][68]
    float* Wd = sh + 64 * 68;   // [64][68]
    for (int t = tid; t < 4096; t += 256) {
      int r = t >> 6, c = t & 63;
      int gr = jb * 64 + r;
      float v = (r == c) ? fabsf(tdiag[gr])
              : (r > c ? tlow[(size_t)gr * DD + jb * 64 + c] : 0.0f);
      Ld[r * 68 + c] = v;
    }
    __syncthreads();
    if (tid < 64) {
      // thread t owns column t of the inverse
      for (int i = 0; i < 64; i++) {
        float w = (i == tid) ? 1.0f : 0.0f;
        for (int k = 0; k < i; k++) w -= Ld[i * 68 + k] * Wd[k * 68 + tid];
        Wd[i * 68 + tid] = w / Ld[i * 68 + i];
      }
    }
    __syncthreads();
    float* Wblk = W + (size_t)(jb * 64) * DD + jb * 64;
    for (int t = tid; t < 4096; t += 256)
      Wblk[(size_t)(t >> 6) * DD + (t & 63)] = Wd[(t >> 6) * 68 + (t & 63)];
  }
}

// 64x64 NN GEMM tile on caller LDS (stride 68): Cd = sgn * A[:,k0:k1] * B[k0:k1,:]
__device__ __forceinline__ void nn64_sh(float* As, float* Bs,
    const float* __restrict__ A, int lda, const float* __restrict__ B, int ldb,
    float* __restrict__ Cd, int ldc, int k0, int k1, float sgn) {
  int tid = threadIdx.x, tr = tid >> 4, tc = tid & 15;
  float acc[4][4] = {};
  for (int kc = k0; kc < k1; kc += 64) {
    #pragma unroll
    for (int p = 0; p < 4; p++) {
      int f4 = tid + 256 * p;
      int row = f4 >> 4, c4 = f4 & 15;
      *(float4*)&As[row * 68 + c4 * 4] = *(const float4*)(A + (size_t)row * lda + kc + c4 * 4);
      *(float4*)&Bs[row * 68 + c4 * 4] = *(const float4*)(B + (size_t)(kc + row) * ldb + c4 * 4);
    }
    __syncthreads();
    #pragma unroll
    for (int kk = 0; kk < 64; kk++) {
      float a[4];
      #pragma unroll
      for (int x = 0; x < 4; x++) a[x] = As[(tr * 4 + x) * 68 + kk];
      float4 bv = *(const float4*)&Bs[kk * 68 + tc * 4];
      float bb[4] = {bv.x, bv.y, bv.z, bv.w};
      #pragma unroll
      for (int x = 0; x < 4; x++)
        #pragma unroll
        for (int y = 0; y < 4; y++) acc[x][y] += a[x] * bb[y];
    }
    __syncthreads();
  }
  #pragma unroll
  for (int x = 0; x < 4; x++) {
    float4 v = make_float4(sgn * acc[x][0], sgn * acc[x][1],
                           sgn * acc[x][2], sgn * acc[x][3]);
    *(float4*)(Cd + (size_t)(tr * 4 + x) * ldc + tc * 4) = v;
  }
}

#define GBK 16
// ============ triT level 128 fused with xmu partials ============
__global__ __launch_bounds__(256) void k_triT128_xmu(const float* __restrict__ L,
    const float* __restrict__ W, float* __restrict__ T,
    const float* __restrict__ Xq, const float* __restrict__ Mu,
    float* __restrict__ xmup) {
  __shared__ float sh[2 * 64 * 68];
  int b = blockIdx.x, tid = threadIdx.x;
  if (b < 4) {              // triT, s=128: h=64, tiles=1
    int g = b, base = g * 128;
    const float* A = L + (size_t)(base + 64) * DD + base;
    const float* B = W + (size_t)base * DD + base;
    float* Cd = T + (size_t)g * 64 * 64;
    nn64_sh(sh, sh + 64 * 68, A, DD, B, DD, Cd, 64, 0, 64, 1.0f);
  } else {                  // xmu partials: 32 q-rows, split-K=4
    float* As = sh;               // stride 36, 16 rows
    float* Bs = sh + 16 * 36;     // stride 68, 16 rows
    int xb = b - 4;
    int bm = (xb & 63) * 32, kq = xb >> 6;
    int tr = tid >> 4, tc = tid & 15;
    float acc[2][4] = {};
    int k0s = kq * (DD / XKS), k0e = k0s + DD / XKS;
    for (int k0 = k0s; k0 < k0e; k0 += GBK) {
      if (tid < 128) {
        int row = tid >> 2, k4 = tid & 3;
        float4 v = *(const float4*)(Xq + (size_t)(bm + row) * DD + k0 + k4 * 4);
        As[(k4 * 4 + 0) * 36 + row] = v.x; As[(k4 * 4 + 1) * 36 + row] = v.y;
        As[(k4 * 4 + 2) * 36 + row] = v.z; As[(k4 * 4 + 3) * 36 + row] = v.w;
      }
      {
        int row = tid >> 2, k4 = tid & 3;
        float4 v = *(const float4*)(Mu + (size_t)row * DD + k0 + k4 * 4);
        Bs[(k4 * 4 + 0) * 68 + row] = v.x; Bs[(k4 * 4 + 1) * 68 + row] = v.y;
        Bs[(k4 * 4 + 2) * 68 + row] = v.z; Bs[(k4 * 4 + 3) * 68 + row] = v.w;
      }
      __syncthreads();
      #pragma unroll
      for (int kk = 0; kk < GBK; kk++) {
        float a[2] = {As[kk * 36 + tr * 2], As[kk * 36 + tr * 2 + 1]};
        float4 b0 = *(const float4*)&Bs[kk * 68 + tc * 4];
        float bb[4] = {b0.x, b0.y, b0.z, b0.w};
        #pragma unroll
        for (int x = 0; x < 2; x++)
          #pragma unroll
          for (int y = 0; y < 4; y++) acc[x][y] += a[x] * bb[y];
      }
      __syncthreads();
    }
    #pragma unroll
    for (int x = 0; x < 2; x++) {
      int q = bm + tr * 2 + x;
      float4 v = make_float4(acc[x][0], acc[x][1], acc[x][2], acc[x][3]);
      *(float4*)(xmup + ((size_t)kq * QNQ + q) * CNUM + tc * 4) = v;
    }
  }
}

// generic trinv doubling levels
__global__ __launch_bounds__(256) void k_triT(const float* __restrict__ L,
                                              const float* __restrict__ W,
                                              float* __restrict__ T, int s) {
  __shared__ float sh[2 * 64 * 68];
  int h = s >> 1, tiles = h >> 6, per = tiles * tiles;
  int g = blockIdx.x / per, rem = blockIdx.x % per;
  int ti = rem / tiles, tj = rem % tiles;
  int base = g * s;
  const float* A = L + (size_t)(base + h + ti * 64) * DD + base;
  const float* B = W + (size_t)base * DD + base + tj * 64;
  float* Cd = T + (size_t)g * h * h + (size_t)(ti * 64) * h + tj * 64;
  nn64_sh(sh, sh + 64 * 68, A, DD, B, DD, Cd, h, tj * 64, h, 1.0f);
}

__global__ __launch_bounds__(256) void k_triX(float* __restrict__ W,
                                              const float* __restrict__ T, int s) {
  __shared__ float sh[2 * 64 * 68];
  int h = s >> 1, tiles = h >> 6, per = tiles * tiles;
  int g = blockIdx.x / per, rem = blockIdx.x % per;
  int ti = rem / tiles, tj = rem % tiles;
  int base = g * s;
  const float* A = W + (size_t)(base + h + ti * 64) * DD + base + h;
  const float* B = T + (size_t)g * h * h + tj * 64;
  float* Cd = W + (size_t)(base + h + ti * 64) * DD + base + tj * 64;
  nn64_sh(sh, sh + 64 * 68, A, DD, B, h, Cd, DD, 0, (ti + 1) * 64, -1.0f);
}

// ============ F3: Y-GEMM (64x64, tri-skip) + wm (one launch) ============
__global__ __launch_bounds__(256) void f_y_wm(const float* __restrict__ Xq,
    const float* __restrict__ Xs, const float* __restrict__ Mu,
    const float* __restrict__ W, const float* __restrict__ m,
    float* __restrict__ Y, float* __restrict__ wm) {
  __shared__ float As[GBK][68];
  __shared__ float Bs[GBK][68];
  int b = blockIdx.x, tid = threadIdx.x;
  if (b < 392) {            // Y = [Xq; Xs; mu] @ W^T; 49 m-tiles x 8 n-tiles
    int mt = b >> 3, nt = b & 7;
    int bm = mt * 64, bn = nt * 64;
    const float* A; int aOff;
    if (bm < QNQ)             { A = Xq; aOff = bm; }
    else if (bm < QNQ + NSUP) { A = Xs; aOff = bm - QNQ; }
    else                      { A = Mu; aOff = bm - QNQ - NSUP; }
    int tr = tid >> 4, tc = tid & 15;
    float acc[4][4] = {};
    int kend = bn + 64;     // W lower-triangular
    for (int k0 = 0; k0 < kend; k0 += GBK) {
      int row = tid >> 2, k4 = tid & 3;
      float4 v = *(const float4*)(A + (size_t)(aOff + row) * DD + k0 + k4 * 4);
      As[k4 * 4 + 0][row] = v.x; As[k4 * 4 + 1][row] = v.y;
      As[k4 * 4 + 2][row] = v.z; As[k4 * 4 + 3][row] = v.w;
      float4 w = *(const float4*)(W + (size_t)(bn + row) * DD + k0 + k4 * 4);
      Bs[k4 * 4 + 0][row] = w.x; Bs[k4 * 4 + 1][row] = w.y;
      Bs[k4 * 4 + 2][row] = w.z; Bs[k4 * 4 + 3][row] = w.w;
      __syncthreads();
      #pragma unroll
      for (int kk = 0; kk < GBK; kk++) {
        float4 a0 = *(const float4*)&As[kk][tr * 4];
        float4 b0 = *(const float4*)&Bs[kk][tc * 4];
        float a[4] = {a0.x, a0.y, a0.z, a0.w};
        float bb[4] = {b0.x, b0.y, b0.z, b0.w};
        #pragma unroll
        for (int x = 0; x < 4; x++)
          #pragma unroll
          for (int y = 0; y < 4; y++) acc[x][y] += a[x] * bb[y];
      }
      __syncthreads();
    }
    #pragma unroll
    for (int x = 0; x < 4; x++) {
      float4 v = make_float4(acc[x][0], acc[x][1], acc[x][2], acc[x][3]);
      *(float4*)(Y + (size_t)(bm + tr * 4 + x) * DD + bn + tc * 4) = v;
    }
  } else {                  // wm[row] = W[row,:] . m  (4 rows/block)
    int wave = tid >> 6, lane = tid & 63;
    int row = (b - 392) * 4 + wave;
    float s = 0.0f;
    for (int j = lane; j < DD; j += 64) s += W[(size_t)row * DD + j] * m[j];
    for (int off = 32; off > 0; off >>= 1) s += __shfl_down(s, off);
    if (lane == 0) wm[row] = s;
  }
}

// fused: blocks 0..511 compute u[j]; block 512 computes SM consts
__global__ __launch_bounds__(256) void k_uB(const float* W, const float* L,
                                            const float* wm, float* u, float* cst) {
  __shared__ float red[256];
  __shared__ float red2[256];
  int b = blockIdx.x, tid = threadIdx.x;
  if (b < DD) {
    float s = 0.0f;
    for (int i = tid; i < DD; i += 256) s += W[(size_t)i * DD + b] * wm[i];
    red[tid] = s;
    __syncthreads();
    for (int off = 128; off > 0; off >>= 1) {
      if (tid < off) red[tid] += red[tid + off];
      __syncthreads();
    }
    if (tid == 0) u[b] = red[0];
  } else {
    float a = 0.0f, l = 0.0f;
    for (int t = tid; t < DD; t += 256) {
      float w = wm[t]; a += w * w;
      l += logf(fabsf(L[(size_t)t * DD + t]));
    }
    red[tid] = a; red2[tid] = l;
    __syncthreads();
    for (int off = 128; off > 0; off >>= 1) {
      if (tid < off) { red[tid] += red[tid + off]; red2[tid] += red2[tid + off]; }
      __syncthreads();
    }
    if (tid == 0) {
      float kap = cst[0], ss = red[0];
      cst[10] = kap / (1.0f + kap * ss);
      cst[11] = 2.0f * red2[0] + logf(1.0f + kap * ss);
    }
  }
}

// ============ F5: Rg GEMM + query z/qn/qB + gram/minv (one launch) ============
__global__ __launch_bounds__(256) void f_z_rg_gram(const float* __restrict__ Y,
    const int* __restrict__ rowmap, const float* __restrict__ Xq,
    const float* __restrict__ u, const float* __restrict__ wm,
    const float* __restrict__ cst,
    float* __restrict__ Rg, float* __restrict__ Rg2,
    float* __restrict__ z, float* __restrict__ qn, float* __restrict__ qB,
    float* __restrict__ zg, float* __restrict__ Vmu, float* __restrict__ muBmu,
    float* __restrict__ Minv, float* __restrict__ bias) {
  __shared__ float sh[2880];
  __shared__ int pivrow;
  __shared__ float detacc;
  int b = blockIdx.x, tid = threadIdx.x;
  if (b < 1088) {           // Rg: 17 m-tiles x 32 n-tiles x 2 K-halves, 64x64 out
    float* As = sh;            // stride 68
    float* Bs = sh + 1088;
    int half = b / 544, rem = b % 544;
    int bm = (rem >> 5) * 64, bn = (rem & 31) * 64;
    float* out = half ? Rg2 : Rg;
    int tr = tid >> 4, tc = tid & 15;
    int srow = rowmap[bm + (tid >> 2)];
    float acc[4][4] = {};
    int k0s = half * 256;
    for (int k0 = k0s; k0 < k0s + 256; k0 += GBK) {
      int row = tid >> 2, k4 = tid & 3;
      float4 v = *(const float4*)(Y + (size_t)srow * DD + k0 + k4 * 4);
      As[(k4 * 4 + 0) * 68 + row] = v.x; As[(k4 * 4 + 1) * 68 + row] = v.y;
      As[(k4 * 4 + 2) * 68 + row] = v.z; As[(k4 * 4 + 3) * 68 + row] = v.w;
      float4 w = *(const float4*)(Y + (size_t)(bn + row) * DD + k0 + k4 * 4);
      Bs[(k4 * 4 + 0) * 68 + row] = w.x; Bs[(k4 * 4 + 1) * 68 + row] = w.y;
      Bs[(k4 * 4 + 2) * 68 + row] = w.z; Bs[(k4 * 4 + 3) * 68 + row] = w.w;
      __syncthreads();
      #pragma unroll
      for (int kk = 0; kk < GBK; kk++) {
        float4 a0 = *(const float4*)&As[kk * 68 + tr * 4];
        float4 b0 = *(const float4*)&Bs[kk * 68 + tc * 4];
        float a[4] = {a0.x, a0.y, a0.z, a0.w};
        float bb[4] = {b0.x, b0.y, b0.z, b0.w};
        #pragma unroll
        for (int x = 0; x < 4; x++)
          #pragma unroll
          for (int y = 0; y < 4; y++) acc[x][y] += a[x] * bb[y];
      }
      __syncthreads();
    }
    #pragma unroll
    for (int x = 0; x < 4; x++) {
      float4 v = make_float4(acc[x][0], acc[x][1], acc[x][2], acc[x][3]);
      *(float4*)(out + (size_t)(bm + tr * 4 + x) * QNQ + bn + tc * 4) = v;
    }
  } else if (b < 1600) {    // query rows only: z, qn, qB
    int wave = tid >> 6, lane = tid & 63;
    int row = (b - 1088) * 4 + wave;
    const float* src = Xq + (size_t)row * DD;
    const float* yr = Y + (size_t)row * DD;
    float s = 0.0f, s1 = 0.0f, s2 = 0.0f;
    for (int j4 = lane; j4 < 128; j4 += 64) {
      float4 v = *(const float4*)(src + j4 * 4);
      float4 uu = *(const float4*)(u + j4 * 4);
      s += v.x * uu.x + v.y * uu.y + v.z * uu.z + v.w * uu.w;
      s1 += v.x * v.x + v.y * v.y + v.z * v.z + v.w * v.w;
      float4 yv = *(const float4*)(yr + j4 * 4);
      s2 += yv.x * yv.x + yv.y * yv.y + yv.z * yv.z + yv.w * yv.w;
    }
    for (int off = 32; off > 0; off >>= 1) {
      s += __shfl_down(s, off);
      s1 += __shfl_down(s1, off);
      s2 += __shfl_down(s2, off);
    }
    if (lane == 0) {
      z[row] = s;
      qn[row] = s1;
      qB[row] = s2 - cst[10] * s * s;
    }
  } else {                  // gram + 17x17 GJ inverse + bias, chunked (zs = Y.wm)
    int c = b - 1600;
    float* Yc   = sh;                 // 17 x 132
    float* aug  = sh + 2244;          // 17 x 35
    float* zacc = sh + 2244 + 595;    // 17
    float* colk = sh + 2244 + 595 + 17; // 17
    int e0 = tid, e1 = tid + 256;
    float g0 = 0.0f, g1 = 0.0f;
    if (tid < 17) zacc[tid] = 0.0f;
    __syncthreads();
    int wave = tid >> 6, lane = tid & 63;
    for (int ch = 0; ch < 4; ch++) {
      for (int t = tid; t < 17 * 32; t += 256) {
        int r = t >> 5, col = t & 31;
        *(float4*)&Yc[r * 132 + col * 4] =
            *(const float4*)(Y + (size_t)rowmap[c * 17 + r] * DD + ch * 128 + col * 4);
      }
      __syncthreads();
      // zs partial: wave w owns rows {w, w+4, ...}; zs = Y_row . wm
      for (int a = wave; a < 17; a += 4) {
        float s = Yc[a * 132 + lane] * wm[ch * 128 + lane]
                + Yc[a * 132 + 64 + lane] * wm[ch * 128 + 64 + lane];
        for (int off = 32; off > 0; off >>= 1) s += __shfl_down(s, off);
        if (lane == 0) zacc[a] += s;
      }
      // Gram partials: each thread owns up to 2 entries
      {
        int a = e0 / 17, bb = e0 % 17;
        const float* ra = &Yc[a * 132];
        const float* rb = &Yc[bb * 132];
        float s = 0.0f;
        for (int k = 0; k < 32; k++) {
          float4 va = *(const float4*)&ra[k * 4];
          float4 vb = *(const float4*)&rb[k * 4];
          s += va.x * vb.x + va.y * vb.y + va.z * vb.z + va.w * vb.w;
        }
        g0 += s;
      }
      if (e1 < 289) {
        int a = e1 / 17, bb = e1 % 17;
        const float* ra = &Yc[a * 132];
        const float* rb = &Yc[bb * 132];
        float s = 0.0f;
        for (int k = 0; k < 32; k++) {
          float4 va = *(const float4*)&ra[k * 4];
          float4 vb = *(const float4*)&rb[k * 4];
          s += va.x * vb.x + va.y * vb.y + va.z * vb.z + va.w * vb.w;
        }
        g1 += s;
      }
      __syncthreads();
    }
    float csm = cst[10];
    {
      int a = e0 / 17, bb = e0 % 17;
      float g = g0 - csm * zacc[a] * zacc[bb];
      if (a == bb) g += (a < 16) ? 1.0f : cst[9];
      aug[a * 35 + bb] = g;
      aug[a * 35 + 17 + bb] = (a == bb) ? 1.0f : 0.0f;
    }
    if (e1 < 289) {
      int a = e1 / 17, bb = e1 % 17;
      float g = g1 - csm * zacc[a] * zacc[bb];
      if (a == bb) g += (a < 16) ? 1.0f : cst[9];
      aug[a * 35 + bb] = g;
      aug[a * 35 + 17 + bb] = (a == bb) ? 1.0f : 0.0f;
    }
    __syncthreads();
    if (tid < 17) {
      float gv = aug[tid * 35 + 16];
      if (tid == 16) gv -= cst[9];
      Vmu[c * 17 + tid] = gv;
      if (tid == 16) muBmu[c] = gv;
      zg[c * 17 + tid] = zacc[tid];
    }
    if (tid == 0) detacc = 0.0f;
    __syncthreads();
    for (int k = 0; k < 17; k++) {
      if (tid == 0) {
        int p = k; float best = fabsf(aug[k * 35 + k]);
        for (int r = k + 1; r < 17; r++) {
          float v = fabsf(aug[r * 35 + k]);
          if (v > best) { best = v; p = r; }
        }
        pivrow = p;
      }
      __syncthreads();
      int p = pivrow;
      if (p != k) {
        for (int cc = tid; cc < 34; cc += 256) {
          float tmp = aug[k * 35 + cc]; aug[k * 35 + cc] = aug[p * 35 + cc]; aug[p * 35 + cc] = tmp;
        }
      }
      __syncthreads();
      if (tid == 0) detacc += logf(fabsf(aug[k * 35 + k]));
      if (tid < 17) colk[tid] = aug[tid * 35 + k];
      __syncthreads();
      float invp = 1.0f / aug[k * 35 + k];
      for (int cc = tid; cc < 34; cc += 256) aug[k * 35 + cc] *= invp;
      __syncthreads();
      for (int t = tid; t < 17 * 34; t += 256) {
        int r = t / 34, cc = t % 34;
        if (r != k) aug[r * 35 + cc] -= colk[r] * aug[k * 35 + cc];
      }
      __syncthreads();
    }
    for (int t = tid; t < 289; t += 256)
      Minv[(size_t)c * 289 + t] = aug[(t / 17) * 35 + 17 + t % 17];
    if (tid == 0) {
      float slog = logf(fabsf(cst[5])) + detacc;
      float logdetSigma = cst[8] + cst[11] + slog;
      bias[c] = cst[4] - 0.5f * logdetSigma;
    }
  }
}

// final epilogue: Woodbury-corrected Mahalanobis -> logits[q,c]
__global__ __launch_bounds__(256) void k_logits(const float* __restrict__ Rg,
    const float* __restrict__ Rg2, const float* z, const float* zg,
    const float* Vmu, const float* muBmu, const float* mun, const float* qB,
    const float* qn, const float* xmup, const float* Minv, const float* bias,
    const float* cst, float* out) {
  __shared__ float Ms[289], Vs[17], Zs[17];
  int c = blockIdx.y;
  int q = blockIdx.x * 256 + threadIdx.x;
  for (int t = threadIdx.x; t < 289; t += 256) Ms[t] = Minv[(size_t)c * 289 + t];
  if (threadIdx.x < 17) {
    Vs[threadIdx.x] = Vmu[c * 17 + threadIdx.x];
    Zs[threadIdx.x] = zg[c * 17 + threadIdx.x];
  }
  __syncthreads();
  float csm = cst[10], scale = cst[1], common = cst[2], coef = cst[3];
  float zq = z[q];
  float r[17];
  float xBmu = 0.0f;
  for (int a = 0; a < 17; a++) {
    size_t off = (size_t)(c * 17 + a) * QNQ + q;
    float raw = Rg[off] + Rg2[off] - csm * Zs[a] * zq;
    if (a == 16) xBmu = raw;
    r[a] = raw - Vs[a];
  }
  float quadB = qB[q] - 2.0f * xBmu + muBmu[c];
  float corr = 0.0f;
  for (int a = 0; a < 17; a++) {
    float e = 0.0f;
    for (int bb = 0; bb < 17; bb++) e += Ms[a * 17 + bb] * r[bb];
    corr += r[a] * e;
  }
  float distB = (quadB - corr) / scale;
  float xm = 0.0f;
  #pragma unroll
  for (int p = 0; p < XKS; p++)
    xm += xmup[((size_t)p * QNQ + q) * CNUM + c];
  float dn = qn[q] - 2.0f * xm + mun[c];
  float dist = (1.0f - REGP) * distB + REGP * dn;
  out[(size_t)q * CNUM + c] = bias[c] - coef * log1pf(dist / common);
}

// ---------------- host ----------------
extern "C" void kernel_launch(void* const* d_in, const int* in_sizes, int n_in,
                              void* d_out, int out_size, void* d_ws, size_t ws_size,
                              hipStream_t stream) {
  const float* Xs    = (const float*)d_in[0];
  const int*   labels= (const int*)d_in[1];
  const float* Xq    = (const float*)d_in[2];
  const float* m     = (const float*)d_in[3];
  const float* kappa = (const float*)d_in[4];
  const float* nu    = (const float*)d_in[5];
  const float* tdiag = (const float*)d_in[6];
  const float* tlow  = (const float*)d_in[7];
  float* ws = (float*)d_ws;
  float* L    = ws + OFF_L;
  float* W    = ws + OFF_W;
  float* mu   = ws + OFF_MU;
  float* Y    = ws + OFF_Y;
  float* z    = ws + OFF_Z;
  float* wm   = ws + OFF_WM;
  float* u    = ws + OFF_U;
  float* cst  = ws + OFF_CONST;
  int*   idx  = (int*)(ws + OFF_IDX);
  int*   rmap = (int*)(ws + OFF_RMAP);
  float* zg   = ws + OFF_ZG;
  float* Vmu  = ws + OFF_VMU;
  float* muBmu= ws + OFF_MUBMU;
  float* mun  = ws + OFF_MUN;
  float* Minv = ws + OFF_MINV;
  float* bias = ws + OFF_BIAS;
  float* qB   = ws + OFF_QB;
  float* qn   = ws + OFF_QNRM;
  float* xmup = ws + OFF_XMU;
  float* Rg   = ws + OFF_RG;
  float* Rg2  = ws + OFF_RG2;
  float* Ttmp = ws + OFF_RG;       // trinv scratch, reused (Rg written later)
  float* out  = (float*)d_out;

  // F1: L/W init + consts + classidx + mu/mun + diag inverses (self-sufficient ranges)
  f_init<<<1161, 256, 0, stream>>>(tdiag, tlow, kappa, nu, labels, Xs, m,
                                   L, W, cst, idx, rmap, mu, mun);
  // trinv recursive doubling; level-128 T fused with xmu partials
  k_triT128_xmu<<<260, 256, 0, stream>>>(L, W, Ttmp, Xq, mu, xmup);
  k_triX<<<4, 256, 0, stream>>>(W, Ttmp, 128);
  k_triT<<<8, 256, 0, stream>>>(L, W, Ttmp, 256);
  k_triX<<<8, 256, 0, stream>>>(W, Ttmp, 256);
  k_triT<<<16, 256, 0, stream>>>(L, W, Ttmp, 512);
  k_triX<<<16, 256, 0, stream>>>(W, Ttmp, 512);
  // Y GEMM (64x64, tri-skip) + wm
  f_y_wm<<<520, 256, 0, stream>>>(Xq, Xs, mu, W, m, Y, wm);
  // u = W^T wm + SM consts
  k_uB<<<513, 256, 0, stream>>>(W, L, wm, u, cst);
  // Rg split-K GEMM + query z/qn/qB + gram/minv/bias
  f_z_rg_gram<<<1664, 256, 0, stream>>>(Y, rmap, Xq, u, wm, cst, Rg, Rg2,
                                        z, qn, qB, zg, Vmu, muBmu, Minv, bias);
  k_logits<<<dim3(QNQ / 256, CNUM), 256, 0, stream>>>(Rg, Rg2, z, zg, Vmu, muBmu,
                                                      mun, qB, qn, xmup, Minv, bias,
                                                      cst, out);
  (void)in_sizes; (void)n_in; (void)out_size; (void)ws_size;
}

// Round 10
// 280.815 us; speedup vs baseline: 2.6382x; 1.0862x over previous
//
#include <hip/hip_runtime.h>
#include <math.h>

// Problem dims (fixed by setup_inputs)
#define DD    512
#define CNUM  64
#define SHOTS 16
#define NSUP  1024
#define QNQ   2048
#define REGP  0.1f
#define XKS   4      // xmu split-K parts

// ---------------- workspace layout (in floats) ----------------
static constexpr size_t OFF_L     = 0;                       // 512*512
static constexpr size_t OFF_W     = OFF_L     + 512*512;     // 512*512
static constexpr size_t OFF_MU    = OFF_W     + 512*512;     // 64*512
static constexpr size_t OFF_Y     = OFF_MU    + 64*512;      // 3136*512
static constexpr size_t OFF_Z     = OFF_Y     + 3136*512;    // 3136
static constexpr size_t OFF_WM    = OFF_Z     + 3136;        // 512
static constexpr size_t OFF_U     = OFF_WM    + 512;         // 512
static constexpr size_t OFF_CONST = OFF_U     + 512;         // 16
static constexpr size_t OFF_IDX   = OFF_CONST + 16;          // 1024 ints
static constexpr size_t OFF_RMAP  = OFF_IDX   + 1024;        // 1088 ints
static constexpr size_t OFF_ZG    = OFF_RMAP  + 1088;        // 1088
static constexpr size_t OFF_VMU   = OFF_ZG    + 1088;        // 1088
static constexpr size_t OFF_MUBMU = OFF_VMU   + 1088;        // 64
static constexpr size_t OFF_MUN   = OFF_MUBMU + 64;          // 64
static constexpr size_t OFF_MINV  = OFF_MUN   + 64;          // 64*289
static constexpr size_t OFF_BIAS  = OFF_MINV  + 64*289;      // 64
static constexpr size_t OFF_QB    = OFF_BIAS  + 64;          // 2048
static constexpr size_t OFF_QNRM  = OFF_QB    + 2048;        // 2048
static constexpr size_t OFF_XMU   = OFF_QNRM  + 2048;        // XKS*2048*64
static constexpr size_t OFF_RG    = OFF_XMU   + (size_t)XKS*2048*64; // 1088*2048
static constexpr size_t OFF_RG2   = OFF_RG    + 1088*2048;   // 1088*2048

// consts: 0 kap, 1 scale, 2 common, 3 coef, 4 bias0, 5 jlast,
// 6 cmu_m, 7 cmu_x, 8 D*log(scale), 9 Jinv_last, 10 c_sm, 11 logdetB

// ============ F1: L/W init + consts + classidx + mu/mun + diag-inv ============
// All block ranges are self-sufficient (no cross-block deps within the launch).
__global__ __launch_bounds__(256) void f_init(const float* tdiag, const float* tlow,
    const float* kappa, const float* nu, const int* labels, const float* Xs,
    const float* m, float* L, float* W, float* cst, int* idx, int* rowmap,
    float* mu, float* mun) {
  __shared__ float sh[2 * 64 * 68];   // 34.8 KB union
  __shared__ int sidx[SHOTS];
  int b = blockIdx.x, tid = threadIdx.x;
  if (b < 1024) {
    int t = b * 256 + tid;
    int i = t >> 9, j = t & 511;
    L[t] = (i == j) ? fabsf(tdiag[i]) : (i > j ? tlow[t] : 0.0f);
    if ((i >> 6) < (j >> 6)) W[t] = 0.0f;   // only strict-upper 64-blocks need zeros
  } else if (b == 1024) {
    if (tid == 0) {
      float kap = fabsf(kappa[0]) + 1e-6f;
      float nu_ = fmaxf(nu[0], (float)(DD - 1) + 1e-6f);
      float common = nu_ + (float)SHOTS + 1.0f - (float)DD;
      float scale = (kap + SHOTS + 1.0f) / ((nu_ + SHOTS - DD + 1.0f) * (kap + SHOTS));
      cst[0] = kap;
      cst[1] = scale;
      cst[2] = common;
      cst[3] = 0.5f * (common + DD);
      cst[4] = lgammaf(0.5f * (common + DD)) - lgammaf(0.5f * common)
               - 0.5f * (float)DD * logf(common);
      cst[5] = -(kap + SHOTS);
      cst[6] = kap / (kap + SHOTS);
      cst[7] = 1.0f / (kap + SHOTS);
      cst[8] = (float)DD * logf(scale);
      cst[9] = -1.0f / (kap + SHOTS);
    }
  } else if (b < 1089) {
    // classidx + rowmap (global)
    int c = b - 1025;
    if (tid < 64) {
      int lane = tid, cnt = 0;
      for (int i0 = 0; i0 < NSUP; i0 += 64) {
        int lab = labels[i0 + lane];
        unsigned long long mm = __ballot(lab == c);
        if (lab == c) {
          int pos = cnt + __popcll(mm & ((1ull << lane) - 1ull));
          if (pos < SHOTS) idx[c * SHOTS + pos] = i0 + lane;
        }
        cnt += __popcll(mm);
      }
    }
    __syncthreads();
    if (tid < 17)
      rowmap[c * 17 + tid] = (tid < SHOTS) ? (QNQ + idx[c * SHOTS + tid])
                                           : (QNQ + NSUP + c);
  } else if (b < 1153) {
    // mu/mun with locally re-derived idx + kappa coefficients
    int c = b - 1089;
    if (tid < 64) {
      int lane = tid, cnt = 0;
      for (int i0 = 0; i0 < NSUP; i0 += 64) {
        int lab = labels[i0 + lane];
        unsigned long long mm = __ballot(lab == c);
        if (lab == c) {
          int pos = cnt + __popcll(mm & ((1ull << lane) - 1ull));
          if (pos < SHOTS) sidx[pos] = i0 + lane;
        }
        cnt += __popcll(mm);
      }
    }
    __syncthreads();
    float kap = fabsf(kappa[0]) + 1e-6f;
    float cm = kap / (kap + SHOTS), cx = 1.0f / (kap + SHOTS);
    float* red = sh;
    float acc = 0.0f;
    for (int d = tid; d < DD; d += 256) {
      float s = 0.0f;
      for (int sh_ = 0; sh_ < SHOTS; sh_++)
        s += Xs[(size_t)sidx[sh_] * DD + d];
      float v = cm * m[d] + cx * s;
      mu[(size_t)c * DD + d] = v;
      acc += v * v;
    }
    red[tid] = acc;
    __syncthreads();
    for (int off = 128; off > 0; off >>= 1) {
      if (tid < off) red[tid] += red[tid + off];
      __syncthreads();
    }
    if (tid == 0) mun[c] = red[0];
  } else {
    // diag 64x64 inverse, L-tile built directly from tdiag/tlow
    int jb = b - 1153;
    float* Ld = sh;             // [64][68]
    float* Wd = sh + 64 * 68;   // [64][68]
    for (int t = tid; t < 4096; t += 256) {
      int r = t >> 6, c = t & 63;
      int gr = jb * 64 + r;
      float v = (r == c) ? fabsf(tdiag[gr])
              : (r > c ? tlow[(size_t)gr * DD + jb * 64 + c] : 0.0f);
      Ld[r * 68 + c] = v;
    }
    __syncthreads();
    if (tid < 64) {
      // thread t owns column t of the inverse
      for (int i = 0; i < 64; i++) {
        float w = (i == tid) ? 1.0f : 0.0f;
        for (int k = 0; k < i; k++) w -= Ld[i * 68 + k] * Wd[k * 68 + tid];
        Wd[i * 68 + tid] = w / Ld[i * 68 + i];
      }
    }
    __syncthreads();
    float* Wblk = W + (size_t)(jb * 64) * DD + jb * 64;
    for (int t = tid; t < 4096; t += 256)
      Wblk[(size_t)(t >> 6) * DD + (t & 63)] = Wd[(t >> 6) * 68 + (t & 63)];
  }
}

// 64x64 NN GEMM tile on caller LDS (stride 68): Cd = sgn * A[:,k0:k1] * B[k0:k1,:]
__device__ __forceinline__ void nn64_sh(float* As, float* Bs,
    const float* __restrict__ A, int lda, const float* __restrict__ B, int ldb,
    float* __restrict__ Cd, int ldc, int k0, int k1, float sgn) {
  int tid = threadIdx.x, tr = tid >> 4, tc = tid & 15;
  float acc[4][4] = {};
  for (int kc = k0; kc < k1; kc += 64) {
    #pragma unroll
    for (int p = 0; p < 4; p++) {
      int f4 = tid + 256 * p;
      int row = f4 >> 4, c4 = f4 & 15;
      *(float4*)&As[row * 68 + c4 * 4] = *(const float4*)(A + (size_t)row * lda + kc + c4 * 4);
      *(float4*)&Bs[row * 68 + c4 * 4] = *(const float4*)(B + (size_t)(kc + row) * ldb + c4 * 4);
    }
    __syncthreads();
    #pragma unroll
    for (int kk = 0; kk < 64; kk++) {
      float a[4];
      #pragma unroll
      for (int x = 0; x < 4; x++) a[x] = As[(tr * 4 + x) * 68 + kk];
      float4 bv = *(const float4*)&Bs[kk * 68 + tc * 4];
      float bb[4] = {bv.x, bv.y, bv.z, bv.w};
      #pragma unroll
      for (int x = 0; x < 4; x++)
        #pragma unroll
        for (int y = 0; y < 4; y++) acc[x][y] += a[x] * bb[y];
    }
    __syncthreads();
  }
  #pragma unroll
  for (int x = 0; x < 4; x++) {
    float4 v = make_float4(sgn * acc[x][0], sgn * acc[x][1],
                           sgn * acc[x][2], sgn * acc[x][3]);
    *(float4*)(Cd + (size_t)(tr * 4 + x) * ldc + tc * 4) = v;
  }
}

#define GBK 16
// ============ triT level 128 fused with xmu partials ============
__global__ __launch_bounds__(256) void k_triT128_xmu(const float* __restrict__ L,
    const float* __restrict__ W, float* __restrict__ T,
    const float* __restrict__ Xq, const float* __restrict__ Mu,
    float* __restrict__ xmup) {
  __shared__ float sh[2 * 64 * 68];
  int b = blockIdx.x, tid = threadIdx.x;
  if (b < 4) {              // triT, s=128: h=64, tiles=1
    int g = b, base = g * 128;
    const float* A = L + (size_t)(base + 64) * DD + base;
    const float* B = W + (size_t)base * DD + base;
    float* Cd = T + (size_t)g * 64 * 64;
    nn64_sh(sh, sh + 64 * 68, A, DD, B, DD, Cd, 64, 0, 64, 1.0f);
  } else {                  // xmu partials: 32 q-rows, split-K=4
    float* As = sh;               // stride 36, 16 rows
    float* Bs = sh + 16 * 36;     // stride 68, 16 rows
    int xb = b - 4;
    int bm = (xb & 63) * 32, kq = xb >> 6;
    int tr = tid >> 4, tc = tid & 15;
    float acc[2][4] = {};
    int k0s = kq * (DD / XKS), k0e = k0s + DD / XKS;
    for (int k0 = k0s; k0 < k0e; k0 += GBK) {
      if (tid < 128) {
        int row = tid >> 2, k4 = tid & 3;
        float4 v = *(const float4*)(Xq + (size_t)(bm + row) * DD + k0 + k4 * 4);
        As[(k4 * 4 + 0) * 36 + row] = v.x; As[(k4 * 4 + 1) * 36 + row] = v.y;
        As[(k4 * 4 + 2) * 36 + row] = v.z; As[(k4 * 4 + 3) * 36 + row] = v.w;
      }
      {
        int row = tid >> 2, k4 = tid & 3;
        float4 v = *(const float4*)(Mu + (size_t)row * DD + k0 + k4 * 4);
        Bs[(k4 * 4 + 0) * 68 + row] = v.x; Bs[(k4 * 4 + 1) * 68 + row] = v.y;
        Bs[(k4 * 4 + 2) * 68 + row] = v.z; Bs[(k4 * 4 + 3) * 68 + row] = v.w;
      }
      __syncthreads();
      #pragma unroll
      for (int kk = 0; kk < GBK; kk++) {
        float a[2] = {As[kk * 36 + tr * 2], As[kk * 36 + tr * 2 + 1]};
        float4 b0 = *(const float4*)&Bs[kk * 68 + tc * 4];
        float bb[4] = {b0.x, b0.y, b0.z, b0.w};
        #pragma unroll
        for (int x = 0; x < 2; x++)
          #pragma unroll
          for (int y = 0; y < 4; y++) acc[x][y] += a[x] * bb[y];
      }
      __syncthreads();
    }
    #pragma unroll
    for (int x = 0; x < 2; x++) {
      int q = bm + tr * 2 + x;
      float4 v = make_float4(acc[x][0], acc[x][1], acc[x][2], acc[x][3]);
      *(float4*)(xmup + ((size_t)kq * QNQ + q) * CNUM + tc * 4) = v;
    }
  }
}

// generic trinv doubling levels
__global__ __launch_bounds__(256) void k_triT(const float* __restrict__ L,
                                              const float* __restrict__ W,
                                              float* __restrict__ T, int s) {
  __shared__ float sh[2 * 64 * 68];
  int h = s >> 1, tiles = h >> 6, per = tiles * tiles;
  int g = blockIdx.x / per, rem = blockIdx.x % per;
  int ti = rem / tiles, tj = rem % tiles;
  int base = g * s;
  const float* A = L + (size_t)(base + h + ti * 64) * DD + base;
  const float* B = W + (size_t)base * DD + base + tj * 64;
  float* Cd = T + (size_t)g * h * h + (size_t)(ti * 64) * h + tj * 64;
  nn64_sh(sh, sh + 64 * 68, A, DD, B, DD, Cd, h, tj * 64, h, 1.0f);
}

__global__ __launch_bounds__(256) void k_triX(float* __restrict__ W,
                                              const float* __restrict__ T, int s) {
  __shared__ float sh[2 * 64 * 68];
  int h = s >> 1, tiles = h >> 6, per = tiles * tiles;
  int g = blockIdx.x / per, rem = blockIdx.x % per;
  int ti = rem / tiles, tj = rem % tiles;
  int base = g * s;
  const float* A = W + (size_t)(base + h + ti * 64) * DD + base + h;
  const float* B = T + (size_t)g * h * h + tj * 64;
  float* Cd = W + (size_t)(base + h + ti * 64) * DD + base + tj * 64;
  nn64_sh(sh, sh + 64 * 68, A, DD, B, h, Cd, DD, 0, (ti + 1) * 64, -1.0f);
}

// ============ F3: Y-GEMM (64x64, tri-skip) + wm (one launch) ============
__global__ __launch_bounds__(256) void f_y_wm(const float* __restrict__ Xq,
    const float* __restrict__ Xs, const float* __restrict__ Mu,
    const float* __restrict__ W, const float* __restrict__ m,
    float* __restrict__ Y, float* __restrict__ wm) {
  __shared__ float As[GBK][68];
  __shared__ float Bs[GBK][68];
  int b = blockIdx.x, tid = threadIdx.x;
  if (b < 392) {            // Y = [Xq; Xs; mu] @ W^T; 49 m-tiles x 8 n-tiles
    int mt = b >> 3, nt = b & 7;
    int bm = mt * 64, bn = nt * 64;
    const float* A; int aOff;
    if (bm < QNQ)             { A = Xq; aOff = bm; }
    else if (bm < QNQ + NSUP) { A = Xs; aOff = bm - QNQ; }
    else                      { A = Mu; aOff = bm - QNQ - NSUP; }
    int tr = tid >> 4, tc = tid & 15;
    float acc[4][4] = {};
    int kend = bn + 64;     // W lower-triangular
    for (int k0 = 0; k0 < kend; k0 += GBK) {
      int row = tid >> 2, k4 = tid & 3;
      float4 v = *(const float4*)(A + (size_t)(aOff + row) * DD + k0 + k4 * 4);
      As[k4 * 4 + 0][row] = v.x; As[k4 * 4 + 1][row] = v.y;
      As[k4 * 4 + 2][row] = v.z; As[k4 * 4 + 3][row] = v.w;
      float4 w = *(const float4*)(W + (size_t)(bn + row) * DD + k0 + k4 * 4);
      Bs[k4 * 4 + 0][row] = w.x; Bs[k4 * 4 + 1][row] = w.y;
      Bs[k4 * 4 + 2][row] = w.z; Bs[k4 * 4 + 3][row] = w.w;
      __syncthreads();
      #pragma unroll
      for (int kk = 0; kk < GBK; kk++) {
        float4 a0 = *(const float4*)&As[kk][tr * 4];
        float4 b0 = *(const float4*)&Bs[kk][tc * 4];
        float a[4] = {a0.x, a0.y, a0.z, a0.w};
        float bb[4] = {b0.x, b0.y, b0.z, b0.w};
        #pragma unroll
        for (int x = 0; x < 4; x++)
          #pragma unroll
          for (int y = 0; y < 4; y++) acc[x][y] += a[x] * bb[y];
      }
      __syncthreads();
    }
    #pragma unroll
    for (int x = 0; x < 4; x++) {
      float4 v = make_float4(acc[x][0], acc[x][1], acc[x][2], acc[x][3]);
      *(float4*)(Y + (size_t)(bm + tr * 4 + x) * DD + bn + tc * 4) = v;
    }
  } else {                  // wm[row] = W[row,:] . m  (4 rows/block)
    int wave = tid >> 6, lane = tid & 63;
    int row = (b - 392) * 4 + wave;
    float s = 0.0f;
    for (int j = lane; j < DD; j += 64) s += W[(size_t)row * DD + j] * m[j];
    for (int off = 32; off > 0; off >>= 1) s += __shfl_down(s, off);
    if (lane == 0) wm[row] = s;
  }
}

// fused: blocks 0..511 compute u[j]; block 512 computes SM consts
__global__ __launch_bounds__(256) void k_uB(const float* W, const float* L,
                                            const float* wm, float* u, float* cst) {
  __shared__ float red[256];
  __shared__ float red2[256];
  int b = blockIdx.x, tid = threadIdx.x;
  if (b < DD) {
    float s = 0.0f;
    for (int i = tid; i < DD; i += 256) s += W[(size_t)i * DD + b] * wm[i];
    red[tid] = s;
    __syncthreads();
    for (int off = 128; off > 0; off >>= 1) {
      if (tid < off) red[tid] += red[tid + off];
      __syncthreads();
    }
    if (tid == 0) u[b] = red[0];
  } else {
    float a = 0.0f, l = 0.0f;
    for (int t = tid; t < DD; t += 256) {
      float w = wm[t]; a += w * w;
      l += logf(fabsf(L[(size_t)t * DD + t]));
    }
    red[tid] = a; red2[tid] = l;
    __syncthreads();
    for (int off = 128; off > 0; off >>= 1) {
      if (tid < off) { red[tid] += red[tid + off]; red2[tid] += red2[tid + off]; }
      __syncthreads();
    }
    if (tid == 0) {
      float kap = cst[0], ss = red[0];
      cst[10] = kap / (1.0f + kap * ss);
      cst[11] = 2.0f * red2[0] + logf(1.0f + kap * ss);
    }
  }
}

// ============ F5: Rg GEMM (64x64, 4x4/thread, split-K=2) + query z/qn/qB ============
__global__ __launch_bounds__(256) void f_z_rg(const float* __restrict__ Y,
    const int* __restrict__ rowmap, const float* __restrict__ Xq,
    const float* __restrict__ u, const float* __restrict__ cst,
    float* __restrict__ Rg, float* __restrict__ Rg2,
    float* __restrict__ z, float* __restrict__ qn, float* __restrict__ qB) {
  __shared__ float As[GBK][68];
  __shared__ float Bs[GBK][68];
  int b = blockIdx.x, tid = threadIdx.x;
  if (b < 1088) {           // 17 m-tiles x 32 n-tiles x 2 K-halves, 64x64 out
    int half = b / 544, rem = b % 544;
    int bm = (rem >> 5) * 64, bn = (rem & 31) * 64;
    float* out = half ? Rg2 : Rg;
    int tr = tid >> 4, tc = tid & 15;
    int srow = rowmap[bm + (tid >> 2)];       // gathered A row for staging
    float acc[4][4] = {};
    int k0s = half * 256;
    for (int k0 = k0s; k0 < k0s + 256; k0 += GBK) {
      int row = tid >> 2, k4 = tid & 3;
      float4 v = *(const float4*)(Y + (size_t)srow * DD + k0 + k4 * 4);
      As[k4 * 4 + 0][row] = v.x; As[k4 * 4 + 1][row] = v.y;
      As[k4 * 4 + 2][row] = v.z; As[k4 * 4 + 3][row] = v.w;
      float4 w = *(const float4*)(Y + (size_t)(bn + row) * DD + k0 + k4 * 4);
      Bs[k4 * 4 + 0][row] = w.x; Bs[k4 * 4 + 1][row] = w.y;
      Bs[k4 * 4 + 2][row] = w.z; Bs[k4 * 4 + 3][row] = w.w;
      __syncthreads();
      #pragma unroll
      for (int kk = 0; kk < GBK; kk++) {
        float4 a0 = *(const float4*)&As[kk][tr * 4];
        float4 b0 = *(const float4*)&Bs[kk][tc * 4];
        float a[4] = {a0.x, a0.y, a0.z, a0.w};
        float bb[4] = {b0.x, b0.y, b0.z, b0.w};
        #pragma unroll
        for (int x = 0; x < 4; x++)
          #pragma unroll
          for (int y = 0; y < 4; y++) acc[x][y] += a[x] * bb[y];
      }
      __syncthreads();
    }
    #pragma unroll
    for (int x = 0; x < 4; x++) {
      float4 v = make_float4(acc[x][0], acc[x][1], acc[x][2], acc[x][3]);
      *(float4*)(out + (size_t)(bm + tr * 4 + x) * QNQ + bn + tc * 4) = v;
    }
  } else {                  // query rows: z, qn, qB (4 rows/block)
    int wave = tid >> 6, lane = tid & 63;
    int row = (b - 1088) * 4 + wave;
    const float* src = Xq + (size_t)row * DD;
    const float* yr = Y + (size_t)row * DD;
    float s = 0.0f, s1 = 0.0f, s2 = 0.0f;
    for (int j4 = lane; j4 < 128; j4 += 64) {
      float4 v = *(const float4*)(src + j4 * 4);
      float4 uu = *(const float4*)(u + j4 * 4);
      s += v.x * uu.x + v.y * uu.y + v.z * uu.z + v.w * uu.w;
      s1 += v.x * v.x + v.y * v.y + v.z * v.z + v.w * v.w;
      float4 yv = *(const float4*)(yr + j4 * 4);
      s2 += yv.x * yv.x + yv.y * yv.y + yv.z * yv.z + yv.w * yv.w;
    }
    for (int off = 32; off > 0; off >>= 1) {
      s += __shfl_down(s, off);
      s1 += __shfl_down(s1, off);
      s2 += __shfl_down(s2, off);
    }
    if (lane == 0) {
      z[row] = s;
      qn[row] = s1;
      qB[row] = s2 - cst[10] * s * s;
    }
  }
}

// ============ F6: per-class Gram (zs = Y.wm in-kernel) + GJ inverse + bias ============
#define YSTRIDE 516
__global__ __launch_bounds__(256) void k_gramminv(const float* Y, const float* wm,
    const int* rowmap, const float* cst, float* zg, float* Vmu, float* muBmu,
    float* Minv, float* bias) {
  __shared__ float Ys[17 * YSTRIDE];
  __shared__ float zs[17];
  __shared__ float aug[17][35];
  __shared__ float colk[17];
  __shared__ int pivrow;
  __shared__ float detacc;
  int c = blockIdx.x, tid = threadIdx.x;
  for (int t = tid; t < 17 * 128; t += 256) {
    int r = t >> 7, col = t & 127;
    *(float4*)&Ys[r * YSTRIDE + col * 4] =
        *(const float4*)(Y + (size_t)rowmap[c * 17 + r] * DD + col * 4);
  }
  __syncthreads();
  // zs[a] = Y_row(a) . wm   (wave w owns rows w, w+4, ...)
  {
    int wave = tid >> 6, lane = tid & 63;
    for (int a = wave; a < 17; a += 4) {
      float s = 0.0f;
      for (int j = lane; j < DD; j += 64) s += Ys[a * YSTRIDE + j] * wm[j];
      for (int off = 32; off > 0; off >>= 1) s += __shfl_down(s, off);
      if (lane == 0) zs[a] = s;
    }
  }
  __syncthreads();
  float csm = cst[10];
  for (int e = tid; e < 289; e += 256) {
    int a = e / 17, bb = e % 17;
    const float* ra = &Ys[a * YSTRIDE];
    const float* rb = &Ys[bb * YSTRIDE];
    float s = 0.0f;
    for (int k = 0; k < 128; k++) {
      float4 va = *(const float4*)&ra[k * 4];
      float4 vb = *(const float4*)&rb[k * 4];
      s += va.x * vb.x + va.y * vb.y + va.z * vb.z + va.w * vb.w;
    }
    float g = s - csm * zs[a] * zs[bb];
    if (a == bb) g += (a < 16) ? 1.0f : cst[9];
    aug[a][bb] = g;
    aug[a][17 + bb] = (a == bb) ? 1.0f : 0.0f;
  }
  __syncthreads();
  if (tid < 17) {
    float gv = aug[tid][16];
    if (tid == 16) gv -= cst[9];
    Vmu[c * 17 + tid] = gv;
    if (tid == 16) muBmu[c] = gv;
    zg[c * 17 + tid] = zs[tid];
  }
  if (tid == 0) detacc = 0.0f;
  __syncthreads();
  for (int k = 0; k < 17; k++) {
    if (tid == 0) {
      int p = k; float best = fabsf(aug[k][k]);
      for (int r = k + 1; r < 17; r++) {
        float v = fabsf(aug[r][k]);
        if (v > best) { best = v; p = r; }
      }
      pivrow = p;
    }
    __syncthreads();
    int p = pivrow;
    if (p != k) {
      for (int cc = tid; cc < 34; cc += 256) {
        float tmp = aug[k][cc]; aug[k][cc] = aug[p][cc]; aug[p][cc] = tmp;
      }
    }
    __syncthreads();
    if (tid == 0) detacc += logf(fabsf(aug[k][k]));
    if (tid < 17) colk[tid] = aug[tid][k];
    __syncthreads();
    float invp = 1.0f / aug[k][k];
    for (int cc = tid; cc < 34; cc += 256) aug[k][cc] *= invp;
    __syncthreads();
    for (int t = tid; t < 17 * 34; t += 256) {
      int r = t / 34, cc = t % 34;
      if (r != k) aug[r][cc] -= colk[r] * aug[k][cc];
    }
    __syncthreads();
  }
  for (int t = tid; t < 289; t += 256) Minv[(size_t)c * 289 + t] = aug[t / 17][17 + t % 17];
  if (tid == 0) {
    float slog = logf(fabsf(cst[5])) + detacc;
    float logdetSigma = cst[8] + cst[11] + slog;
    bias[c] = cst[4] - 0.5f * logdetSigma;
  }
}

// final epilogue: Woodbury-corrected Mahalanobis -> logits[q,c]
__global__ __launch_bounds__(256) void k_logits(const float* __restrict__ Rg,
    const float* __restrict__ Rg2, const float* z, const float* zg,
    const float* Vmu, const float* muBmu, const float* mun, const float* qB,
    const float* qn, const float* xmup, const float* Minv, const float* bias,
    const float* cst, float* out) {
  __shared__ float Ms[289], Vs[17], Zs[17];
  int c = blockIdx.y;
  int q = blockIdx.x * 256 + threadIdx.x;
  for (int t = threadIdx.x; t < 289; t += 256) Ms[t] = Minv[(size_t)c * 289 + t];
  if (threadIdx.x < 17) {
    Vs[threadIdx.x] = Vmu[c * 17 + threadIdx.x];
    Zs[threadIdx.x] = zg[c * 17 + threadIdx.x];
  }
  __syncthreads();
  float csm = cst[10], scale = cst[1], common = cst[2], coef = cst[3];
  float zq = z[q];
  float r[17];
  float xBmu = 0.0f;
  for (int a = 0; a < 17; a++) {
    size_t off = (size_t)(c * 17 + a) * QNQ + q;
    float raw = Rg[off] + Rg2[off] - csm * Zs[a] * zq;
    if (a == 16) xBmu = raw;
    r[a] = raw - Vs[a];
  }
  float quadB = qB[q] - 2.0f * xBmu + muBmu[c];
  float corr = 0.0f;
  for (int a = 0; a < 17; a++) {
    float e = 0.0f;
    for (int bb = 0; bb < 17; bb++) e += Ms[a * 17 + bb] * r[bb];
    corr += r[a] * e;
  }
  float distB = (quadB - corr) / scale;
  float xm = 0.0f;
  #pragma unroll
  for (int p = 0; p < XKS; p++)
    xm += xmup[((size_t)p * QNQ + q) * CNUM + c];
  float dn = qn[q] - 2.0f * xm + mun[c];
  float dist = (1.0f - REGP) * distB + REGP * dn;
  out[(size_t)q * CNUM + c] = bias[c] - coef * log1pf(dist / common);
}

// ---------------- host ----------------
extern "C" void kernel_launch(void* const* d_in, const int* in_sizes, int n_in,
                              void* d_out, int out_size, void* d_ws, size_t ws_size,
                              hipStream_t stream) {
  const float* Xs    = (const float*)d_in[0];
  const int*   labels= (const int*)d_in[1];
  const float* Xq    = (const float*)d_in[2];
  const float* m     = (const float*)d_in[3];
  const float* kappa = (const float*)d_in[4];
  const float* nu    = (const float*)d_in[5];
  const float* tdiag = (const float*)d_in[6];
  const float* tlow  = (const float*)d_in[7];
  float* ws = (float*)d_ws;
  float* L    = ws + OFF_L;
  float* W    = ws + OFF_W;
  float* mu   = ws + OFF_MU;
  float* Y    = ws + OFF_Y;
  float* z    = ws + OFF_Z;
  float* wm   = ws + OFF_WM;
  float* u    = ws + OFF_U;
  float* cst  = ws + OFF_CONST;
  int*   idx  = (int*)(ws + OFF_IDX);
  int*   rmap = (int*)(ws + OFF_RMAP);
  float* zg   = ws + OFF_ZG;
  float* Vmu  = ws + OFF_VMU;
  float* muBmu= ws + OFF_MUBMU;
  float* mun  = ws + OFF_MUN;
  float* Minv = ws + OFF_MINV;
  float* bias = ws + OFF_BIAS;
  float* qB   = ws + OFF_QB;
  float* qn   = ws + OFF_QNRM;
  float* xmup = ws + OFF_XMU;
  float* Rg   = ws + OFF_RG;
  float* Rg2  = ws + OFF_RG2;
  float* Ttmp = ws + OFF_RG;       // trinv scratch, reused (Rg written later)
  float* out  = (float*)d_out;

  // F1: L/W init + consts + classidx + mu/mun + diag inverses (self-sufficient ranges)
  f_init<<<1161, 256, 0, stream>>>(tdiag, tlow, kappa, nu, labels, Xs, m,
                                   L, W, cst, idx, rmap, mu, mun);
  // trinv recursive doubling; level-128 T fused with xmu partials
  k_triT128_xmu<<<260, 256, 0, stream>>>(L, W, Ttmp, Xq, mu, xmup);
  k_triX<<<4, 256, 0, stream>>>(W, Ttmp, 128);
  k_triT<<<8, 256, 0, stream>>>(L, W, Ttmp, 256);
  k_triX<<<8, 256, 0, stream>>>(W, Ttmp, 256);
  k_triT<<<16, 256, 0, stream>>>(L, W, Ttmp, 512);
  k_triX<<<16, 256, 0, stream>>>(W, Ttmp, 512);
  // Y GEMM (64x64, tri-skip) + wm
  f_y_wm<<<520, 256, 0, stream>>>(Xq, Xs, mu, W, m, Y, wm);
  // u = W^T wm + SM consts
  k_uB<<<513, 256, 0, stream>>>(W, L, wm, u, cst);
  // Rg split-K GEMM (lean, VGPR~40) + query z/qn/qB
  f_z_rg<<<1088 + 512, 256, 0, stream>>>(Y, rmap, Xq, u, cst, Rg, Rg2, z, qn, qB);
  // Gram (zs = Y.wm) + 17x17 inverse + bias -- separate kernel, own registers
  k_gramminv<<<64, 256, 0, stream>>>(Y, wm, rmap, cst, zg, Vmu, muBmu, Minv, bias);
  k_logits<<<dim3(QNQ / 256, CNUM), 256, 0, stream>>>(Rg, Rg2, z, zg, Vmu, muBmu,
                                                      mun, qB, qn, xmup, Minv, bias,
                                                      cst, out);
  (void)in_sizes; (void)n_in; (void)out_size; (void)ws_size;
}